// Round 12
// baseline (49.011 us; speedup 1.0000x reference)
//
#include <hip/hip_runtime.h>
#include <hip/hip_bf16.h>

// Conv2dLocal: B=64, C_IN=64, H=W=32, C_OUT=64, 3x3, pad 1, stride 1.
// out[b,o,h,w] = sum_{c,kh,kw} x[b,c,h+kh-1,w+kw-1] * wgt[h,w,o,c,kh,kw] + bias[o,h,w]
//
// xpose_k: x[b][c][y][xw] f32 -> xc[y][xw][b][c] bf16 (8 MB in d_ws)
// conv_k:  block = (h, w-quad) — 256 blocks, 512 thr = 8 waves (2 kh x 4 o4).
//   Loops wi=0..3 over its 4 hw's: per wi, stage im2col patch [64][576] bf16
//   (XOR-swizzled, as before) and run 9 K-steps; per-wave private pinned-asm
//   weight ring (depth 4) runs CONTINUOUSLY across all 36 steps (raw barriers
//   only — __syncthreads would drain vmcnt and kill the ring). acc[4][4] in
//   VGPRs (grid=1 block/CU -> no 128-reg cap). One post-loop kh exchange in
//   LDS (stride 65, scalar, conflict-free), then kh0 threads store out as
//   float4 over the w-quad (16-B chunks; all 8 quads of a row share an XCD
//   via h==bid mod 8, so L2 merges partial lines). Bias fused. This removes
//   the r11 tmpb round-trip AND the trout kernel.

typedef __attribute__((ext_vector_type(8))) short short8;
typedef __attribute__((ext_vector_type(4))) float f32x4;

#define PSTR 576  // patch row stride (bf16) = 72 16B-units; 72%8==0 -> swizzle exact

__device__ __forceinline__ void waitlgkm0() {
  asm volatile("s_waitcnt lgkmcnt(0)" ::: "memory");
}

template <int N>
__device__ __forceinline__ void waitvm() {
  asm volatile("s_waitcnt vmcnt(%0)" ::"i"(N) : "memory");
  __builtin_amdgcn_sched_barrier(0);  // rule #18 fence
}

__device__ __forceinline__ unsigned int bf16rne(float f) {
  unsigned int u = __float_as_uint(f);
  return (u + 0x7FFFu + ((u >> 16) & 1u)) >> 16;
}

__global__ __launch_bounds__(256) void xpose_k(const float* __restrict__ x,
                                               unsigned short* __restrict__ xc) {
  __shared__ float tile[64][65];
  int bid = blockIdx.x;  // 64 row-tiles x 16 col-tiles over A[4096][1024]
  int rt = bid >> 4, ct = bid & 15;
  int r0 = rt << 6, c0 = ct << 6;
  int lane = threadIdx.x & 63, wv = threadIdx.x >> 6;
#pragma unroll
  for (int i = 0; i < 16; ++i) {
    int r = (i << 2) + wv;
    tile[r][lane] = x[(size_t)(r0 + r) * 1024 + c0 + lane];
  }
  __syncthreads();
#pragma unroll
  for (int i = 0; i < 16; ++i) {
    int oc = (i << 2) + wv;
    xc[(size_t)(c0 + oc) * 4096 + r0 + lane] =
        (unsigned short)bf16rne(tile[lane][oc]);
  }
}

__global__ __launch_bounds__(512) void conv_k(const unsigned short* __restrict__ xc,
                                              const float* __restrict__ wgt,
                                              const float* __restrict__ bias,
                                              float* __restrict__ out) {
  extern __shared__ unsigned short patch[];  // [64][PSTR] = 73,728 B dynamic

  int bid = blockIdx.x;  // 256 blocks = 32 h x 8 w-quads; h == bid (mod 8)
  int h = (bid & 7) | (((bid >> 3) & 3) << 3);
  int wq = bid >> 5;  // 0..7
  int t = threadIdx.x;

  int wid = t >> 6, lane = t & 63;
  int o4 = wid & 3, kh = wid >> 2;  // o-tile, K-half
  int l15 = lane & 15, l4 = lane >> 4;
  int l7 = l15 & 7;
  int kh9 = kh * 9;

  // weight row base per wi (static-indexed array -> registers)
  const float* wpA[4];
#pragma unroll
  for (int wi = 0; wi < 4; ++wi)
    wpA[wi] = wgt + (size_t)(h * 32 + wq * 4 + wi) * 36864 +
              (size_t)(o4 * 16 + l15) * 576 + kh * 288 + l4 * 8;

  // staging: thread t owns patch row t>>3, c-octet t&7 (same as r11)
  int c8 = t & 7;
  int prow = t >> 3;
  unsigned short* sdst = patch + prow * PSTR;
  int r7b = prow & 7;
  auto stage = [&](int w) {
    uint4 v[9];
#pragma unroll
    for (int tap = 0; tap < 9; ++tap) {
      int y = h + tap / 3 - 1;
      int xw = w + tap % 3 - 1;
      bool valid = ((unsigned)y < 32u) && ((unsigned)xw < 32u);
      uint4 val = make_uint4(0u, 0u, 0u, 0u);
      if (valid)
        val = *(const uint4*)(xc + ((size_t)(y * 32 + xw) << 12) + prow * 64 + c8 * 8);
      v[tap] = val;
    }
    const unsigned int* vw = (const unsigned int*)v;
#pragma unroll
    for (int u = 0; u < 9; ++u) {
      unsigned int wd[4];
#pragma unroll
      for (int wi2 = 0; wi2 < 4; ++wi2) {
        const int kl0 = 8 * u + 2 * wi2, kl1 = kl0 + 1;
        const int tapA = kl0 % 9, jA = kl0 / 9;
        const int tapB = kl1 % 9, jB = kl1 / 9;
        const unsigned int selLo = (jA & 1) ? 0x0302u : 0x0100u;
        const unsigned int selHi = (jB & 1) ? 0x0706u : 0x0504u;
        wd[wi2] = __builtin_amdgcn_perm(vw[tapB * 4 + (jB >> 1)],
                                        vw[tapA * 4 + (jA >> 1)],
                                        selLo | (selHi << 16));
      }
      int u_abs = 9 * c8 + u;
      int u_swz = (u_abs & ~7) | ((u_abs & 7) ^ r7b);
      *(uint4*)(sdst + (u_swz << 3)) = make_uint4(wd[0], wd[1], wd[2], wd[3]);
    }
  };

  float4 pf[4][2];  // depth-4 ring; static indices only

#define ISSUE(slot, addr)                                              \
  do {                                                                 \
    asm volatile("global_load_dwordx4 %0, %2, off\n\t"                 \
                 "global_load_dwordx4 %1, %2, off offset:16"           \
                 : "=&v"(pf[slot][0]), "=&v"(pf[slot][1])              \
                 : "v"(addr)                                           \
                 : "memory");                                          \
  } while (0)

  // A-read bases (swizzled): K-step S unit low3 = (4*(S&1)+l4)^l7
  const unsigned short* apE = patch + l15 * PSTR + ((l4 ^ l7) << 3);
  const unsigned short* apO = patch + l15 * PSTR + (((4 + l4) ^ l7) << 3);

  f32x4 acc[4][4];
#pragma unroll
  for (int wi = 0; wi < 4; ++wi)
#pragma unroll
    for (int n = 0; n < 4; ++n) acc[wi][n] = (f32x4){0.f, 0.f, 0.f, 0.f};

  union S8U { short8 s; unsigned int u[4]; };
  auto pack = [](const float4& lo, const float4& hi) -> short8 {
    S8U r;  // truncate f32->bf16 via v_perm (weights)
    r.u[0] = __builtin_amdgcn_perm(__float_as_uint(lo.y), __float_as_uint(lo.x), 0x07060302u);
    r.u[1] = __builtin_amdgcn_perm(__float_as_uint(lo.w), __float_as_uint(lo.z), 0x07060302u);
    r.u[2] = __builtin_amdgcn_perm(__float_as_uint(hi.y), __float_as_uint(hi.x), 0x07060302u);
    r.u[3] = __builtin_amdgcn_perm(__float_as_uint(hi.w), __float_as_uint(hi.z), 0x07060302u);
    return r.s;
  };

  // ---- wi = 0 staging + ring prologue ----
  stage(wq * 4);
  ISSUE(0, wpA[0]);       // g=0
  ISSUE(1, wpA[0] + 32);  // g=1
  ISSUE(2, wpA[0] + 64);  // g=2
  ISSUE(3, wpA[0] + 96);  // g=3
  waitlgkm0();
  __builtin_amdgcn_sched_barrier(0);
  __builtin_amdgcn_s_barrier();  // patch(0) visible; ring in flight

  // ---- 4 wi x 9 K-steps; ring continuous; raw barriers only ----
#pragma unroll
  for (int wi = 0; wi < 4; ++wi) {
    if (wi > 0) {
      stage(wq * 4 + wi);
      waitlgkm0();
      __builtin_amdgcn_sched_barrier(0);
      __builtin_amdgcn_s_barrier();  // patch(wi) visible to all
    }
#pragma unroll
    for (int s = 0; s < 9; ++s) {
      const int g = wi * 9 + s;
      if      (g <= 32) waitvm<6>();
      else if (g == 33) waitvm<4>();
      else if (g == 34) waitvm<2>();
      else              waitvm<0>();

      const int slot = g & 3;
      short8 b0 = pack(pf[slot][0], pf[slot][1]);

      int S = kh9 + s;  // K-step 0..17 within patch
      const unsigned short* ab = ((S & 1) ? apO : apE) + (S >> 1) * 64;
      short8 a0 = *(const short8*)ab;
      short8 a1 = *(const short8*)(ab + 16 * PSTR);
      short8 a2 = *(const short8*)(ab + 32 * PSTR);
      short8 a3 = *(const short8*)(ab + 48 * PSTR);

      const int gt = g + 4;
      if (gt <= 35) {
        const int wit = gt / 9, st = gt % 9;   // compile-time constants
        ISSUE(slot, wpA[wit] + st * 32);       // refill slot just consumed
      }

      acc[wi][0] = __builtin_amdgcn_mfma_f32_16x16x32_bf16(a0, b0, acc[wi][0], 0, 0, 0);
      acc[wi][1] = __builtin_amdgcn_mfma_f32_16x16x32_bf16(a1, b0, acc[wi][1], 0, 0, 0);
      acc[wi][2] = __builtin_amdgcn_mfma_f32_16x16x32_bf16(a2, b0, acc[wi][2], 0, 0, 0);
      acc[wi][3] = __builtin_amdgcn_mfma_f32_16x16x32_bf16(a3, b0, acc[wi][3], 0, 0, 0);
    }
    // all waves done reading patch(wi) (MFMA consumption lgkm-waited) before
    // next stage overwrites it / exchange reuses it
    waitlgkm0();
    __builtin_amdgcn_sched_barrier(0);
    __builtin_amdgcn_s_barrier();
  }
#undef ISSUE

  // ---- kh exchange in LDS (stride 65: conflict-free scalar) ----
  float* X = (float*)patch;
  int idx = (o4 << 6) + lane;  // 0..255, matches across kh halves
  if (kh == 1) {
#pragma unroll
    for (int wi = 0; wi < 4; ++wi)
#pragma unroll
      for (int n = 0; n < 4; ++n)
#pragma unroll
        for (int r = 0; r < 4; ++r)
          X[idx * 65 + wi * 16 + (n << 2) + r] = acc[wi][n][r];
  }
  waitlgkm0();
  __builtin_amdgcn_sched_barrier(0);
  __builtin_amdgcn_s_barrier();

  // ---- epilogue (kh0 threads): add partials + bias, float4 over w-quad ----
  if (kh == 0) {
    int o = (o4 << 4) + l15;
    const float4 bb = *(const float4*)(bias + (size_t)o * 1024 + h * 32 + wq * 4);
#pragma unroll
    for (int n = 0; n < 4; ++n) {
#pragma unroll
      for (int r = 0; r < 4; ++r) {
        int b = (n << 4) + (l4 << 2) + r;  // C/D: row=(lane>>4)*4+reg per 16-tile n
        float4 val;
        val.x = acc[0][n][r] + X[idx * 65 + 0 * 16 + (n << 2) + r] + bb.x;
        val.y = acc[1][n][r] + X[idx * 65 + 1 * 16 + (n << 2) + r] + bb.y;
        val.z = acc[2][n][r] + X[idx * 65 + 2 * 16 + (n << 2) + r] + bb.z;
        val.w = acc[3][n][r] + X[idx * 65 + 3 * 16 + (n << 2) + r] + bb.w;
        *(float4*)(out + ((size_t)(b * 64 + o) << 10) + h * 32 + wq * 4) = val;
      }
    }
  }
}

extern "C" void kernel_launch(void* const* d_in, const int* in_sizes, int n_in,
                              void* d_out, int out_size, void* d_ws, size_t ws_size,
                              hipStream_t stream) {
  const float* x = (const float*)d_in[0];
  const float* wgt = (const float*)d_in[1];
  const float* bias = (const float*)d_in[2];
  float* out = (float*)d_out;
  unsigned short* xc = (unsigned short*)d_ws;  // 8,388,608 B

  const int conv_lds = 64 * PSTR * 2;  // 73,728 B dynamic LDS
  (void)hipFuncSetAttribute((const void*)conv_k,
                            hipFuncAttributeMaxDynamicSharedMemorySize, conv_lds);

  hipLaunchKernelGGL(xpose_k, dim3(1024), dim3(256), 0, stream, x, xc);
  hipLaunchKernelGGL(conv_k, dim3(256), dim3(512), conv_lds, stream, xc, wgt, bias, out);
}

// Round 13
// 44.181 us; speedup vs baseline: 1.1093x; 1.1093x over previous
//
#include <hip/hip_runtime.h>
#include <hip/hip_bf16.h>

// Conv2dLocal: B=64, C_IN=64, H=W=32, C_OUT=64, 3x3, pad 1, stride 1.
// out[b,o,h,w] = sum_{c,kh,kw} x[b,c,h+kh-1,w+kw-1] * wgt[h,w,o,c,kh,kw] + bias[o,h,w]
//
// REVERT to round-11 structure (r12's w-quad merge cost occupancy: 1 block/CU,
// serial in-block staging — net −4.75 µs). r11 conv_k byte-identical here.
//
// xpose_k (vectorized): x[b*64+c][hw] f32 -> xc[hw][b*64+c] bf16. 128-row
//   tiles; LDS written transposed at load (column writes (2l+r)%32 = 2-way,
//   free), store reads float2 (2-way free) + writes packed u32 = 256 B/wave.
// conv_k:  one block per hw (grid 1024, 512 thr = 8 waves = 2 kh x 4 o4).
//   Patch [64][576] bf16 XOR-swizzled; per-wave private pinned-asm weight
//   ring (depth 4), counted vmcnt, no barriers in K-loop; C[64][64] f32
//   assembled in LDS, packed bf16, ONE contiguous 8-KB burst to tmpb.
// trout_k (vectorized): tmpb[hw][bo] bf16 -> out[bo][hw] f32; uint loads
//   (2 bf16/lane), transposed LDS scatter (2-way free), fused bias.

typedef __attribute__((ext_vector_type(8))) short short8;
typedef __attribute__((ext_vector_type(4))) float f32x4;

#define PSTR 576  // patch row stride (bf16) = 72 16B-units; 72%8==0 -> swizzle exact

__device__ __forceinline__ void waitlgkm0() {
  asm volatile("s_waitcnt lgkmcnt(0)" ::: "memory");
}

template <int N>
__device__ __forceinline__ void waitvm() {
  asm volatile("s_waitcnt vmcnt(%0)" ::"i"(N) : "memory");
  __builtin_amdgcn_sched_barrier(0);  // rule #18 fence
}

__device__ __forceinline__ unsigned int bf16rne(float f) {
  unsigned int u = __float_as_uint(f);
  return (u + 0x7FFFu + ((u >> 16) & 1u)) >> 16;
}

__global__ __launch_bounds__(256) void xpose_k(const float* __restrict__ x,
                                               unsigned short* __restrict__ xc) {
  __shared__ float tile[64][130];  // [hw][bc], 33,280 B
  int bid = blockIdx.x;            // 32 row-tiles(128 bc) x 16 col-tiles(64 hw)
  int rt = bid >> 4, ct = bid & 15;
  int r0 = rt << 7, c0 = ct << 6;
  int lane = threadIdx.x & 63, wv = threadIdx.x >> 6;
#pragma unroll
  for (int i = 0; i < 32; ++i) {
    int r = (i << 2) + wv;  // bc row 0..127
    tile[lane][r] = x[(size_t)(r0 + r) * 1024 + c0 + lane];  // transposed write
  }
  __syncthreads();
#pragma unroll
  for (int i = 0; i < 16; ++i) {
    int oc = (i << 2) + wv;  // hw col 0..63
    float2 v = *(const float2*)&tile[oc][2 * lane];
    unsigned int pk = bf16rne(v.x) | (bf16rne(v.y) << 16);
    *(unsigned int*)(xc + (size_t)(c0 + oc) * 4096 + r0 + 2 * lane) = pk;
  }
}

__global__ __launch_bounds__(512, 4) void conv_k(const unsigned short* __restrict__ xc,
                                                 const float* __restrict__ wgt,
                                                 unsigned short* __restrict__ tmpb) {
  extern __shared__ unsigned short patch[];  // [64][PSTR] = 73,728 B dynamic

  int bid = blockIdx.x;
  int hw = ((bid & 7) << 7) | (bid >> 3);  // XCD gets 128 contiguous hw
  int h = hw >> 5, w = hw & 31;
  int t = threadIdx.x;

  // ---- stage im2col patch: thread t owns row t>>3, c-octet t&7 ----
  {
    int c8 = t & 7;
    int row = t >> 3;  // 0..63
    uint4 v[9];
#pragma unroll
    for (int tap = 0; tap < 9; ++tap) {
      int y = h + tap / 3 - 1;
      int xw = w + tap % 3 - 1;
      bool valid = ((unsigned)y < 32u) && ((unsigned)xw < 32u);
      uint4 val = make_uint4(0u, 0u, 0u, 0u);
      if (valid)
        val = *(const uint4*)(xc + ((size_t)(y * 32 + xw) << 12) + row * 64 + c8 * 8);
      v[tap] = val;
    }
    unsigned short* dst = patch + row * PSTR;
    int r7b = row & 7;
    const unsigned int* vw = (const unsigned int*)v;
#pragma unroll
    for (int u = 0; u < 9; ++u) {
      unsigned int wd[4];
#pragma unroll
      for (int wi = 0; wi < 4; ++wi) {
        const int kl0 = 8 * u + 2 * wi, kl1 = kl0 + 1;
        const int tapA = kl0 % 9, jA = kl0 / 9;
        const int tapB = kl1 % 9, jB = kl1 / 9;
        const unsigned int selLo = (jA & 1) ? 0x0302u : 0x0100u;
        const unsigned int selHi = (jB & 1) ? 0x0706u : 0x0504u;
        wd[wi] = __builtin_amdgcn_perm(vw[tapB * 4 + (jB >> 1)],
                                       vw[tapA * 4 + (jA >> 1)],
                                       selLo | (selHi << 16));
      }
      int u_abs = 9 * c8 + u;
      int u_swz = (u_abs & ~7) | ((u_abs & 7) ^ r7b);
      *(uint4*)(dst + (u_swz << 3)) = make_uint4(wd[0], wd[1], wd[2], wd[3]);
    }
  }

  // ---- per-wave private weight stream: pinned asm loads, DEPTH-4 ring ----
  int wid = t >> 6, lane = t & 63;
  int o4 = wid & 3, kh = wid >> 2;            // o-tile, K-half
  int l15 = lane & 15, l4 = lane >> 4;
  const float* wb = wgt + (size_t)hw * 36864;  // [64 o][576 k] f32
  const float* wp = wb + (size_t)(o4 * 16 + l15) * 576 + kh * 288 + l4 * 8;

  float4 pf[4][2];  // 32 VGPRs; all indices static after unroll -> registers

#define ISSUE(slot, step)                                              \
  do {                                                                 \
    const float* _a = wp + (step) * 32;                                \
    asm volatile("global_load_dwordx4 %0, %2, off\n\t"                 \
                 "global_load_dwordx4 %1, %2, off offset:16"           \
                 : "=&v"(pf[slot][0]), "=&v"(pf[slot][1])              \
                 : "v"(_a)                                             \
                 : "memory");                                          \
  } while (0)

  ISSUE(0, 0); ISSUE(1, 1); ISSUE(2, 2); ISSUE(3, 3);

  waitlgkm0();                          // own patch ds_writes complete
  __builtin_amdgcn_sched_barrier(0);
  __builtin_amdgcn_s_barrier();         // patch visible; 8 weight loads in flight

  int l7 = l15 & 7;
  const unsigned short* apE = patch + l15 * PSTR + ((l4 ^ l7) << 3);
  const unsigned short* apO = patch + l15 * PSTR + (((4 + l4) ^ l7) << 3);
  int kh9 = kh * 9;

  f32x4 acc0 = {0.f, 0.f, 0.f, 0.f};
  f32x4 acc1 = acc0, acc2 = acc0, acc3 = acc0;

  union S8U { short8 s; unsigned int u[4]; };
  auto pack = [](const float4& lo, const float4& hi) -> short8 {
    S8U r;  // truncate f32->bf16 via v_perm (weights)
    r.u[0] = __builtin_amdgcn_perm(__float_as_uint(lo.y), __float_as_uint(lo.x), 0x07060302u);
    r.u[1] = __builtin_amdgcn_perm(__float_as_uint(lo.w), __float_as_uint(lo.z), 0x07060302u);
    r.u[2] = __builtin_amdgcn_perm(__float_as_uint(hi.y), __float_as_uint(hi.x), 0x07060302u);
    r.u[3] = __builtin_amdgcn_perm(__float_as_uint(hi.w), __float_as_uint(hi.z), 0x07060302u);
    return r.s;
  };

  // 9 K-steps/wave, NO barriers. 18 loads: 8 prologue + 2*5 refills (s=0..4).
  // N = issued - 2(s+1) = 6,6,6,6,6,6,4,2,0.
#pragma unroll
  for (int s = 0; s < 9; ++s) {
    const int slot = s & 3;
    if      (s <= 5) waitvm<6>();
    else if (s == 6) waitvm<4>();
    else if (s == 7) waitvm<2>();
    else             waitvm<0>();

    short8 b0 = pack(pf[slot][0], pf[slot][1]);

    int S = kh9 + s;  // global K-step 0..17 (wave-uniform)
    const unsigned short* ab = ((S & 1) ? apO : apE) + (S >> 1) * 64;
    short8 a0 = *(const short8*)ab;                 // ds_read_b128 x4
    short8 a1 = *(const short8*)(ab + 16 * PSTR);
    short8 a2 = *(const short8*)(ab + 32 * PSTR);
    short8 a3 = *(const short8*)(ab + 48 * PSTR);

    if (s + 4 < 9) ISSUE(slot, s + 4);              // refill slot just consumed

    acc0 = __builtin_amdgcn_mfma_f32_16x16x32_bf16(a0, b0, acc0, 0, 0, 0);
    acc1 = __builtin_amdgcn_mfma_f32_16x16x32_bf16(a1, b0, acc1, 0, 0, 0);
    acc2 = __builtin_amdgcn_mfma_f32_16x16x32_bf16(a2, b0, acc2, 0, 0, 0);
    acc3 = __builtin_amdgcn_mfma_f32_16x16x32_bf16(a3, b0, acc3, 0, 0, 0);
  }
#undef ISSUE

  // ---- assemble C[64 b][64 o] f32 in LDS (stride 68: 2-way-free banks) ----
  __syncthreads();  // all waves done reading patch; ring drained (s=8 -> vmcnt 0)
  float* C = (float*)patch;  // 64*68*4 = 17,408 B, fits in patch region
  int o = (o4 << 4) + l15;
  int m0 = l4 << 2;
  if (kh == 0) {  // C/D layout: col=lane&15 (o), row=(lane>>4)*4+reg (b)
#pragma unroll
    for (int r = 0; r < 4; ++r) {
      C[(m0 + r) * 68 + o] = acc0[r];
      C[(m0 + r + 16) * 68 + o] = acc1[r];
      C[(m0 + r + 32) * 68 + o] = acc2[r];
      C[(m0 + r + 48) * 68 + o] = acc3[r];
    }
  }
  __syncthreads();
  if (kh == 1) {
#pragma unroll
    for (int r = 0; r < 4; ++r) {
      C[(m0 + r) * 68 + o] += acc0[r];
      C[(m0 + r + 16) * 68 + o] += acc1[r];
      C[(m0 + r + 32) * 68 + o] += acc2[r];
      C[(m0 + r + 48) * 68 + o] += acc3[r];
    }
  }
  __syncthreads();

  // ---- contiguous 8-KB bf16 burst: tmpb[hw][b*64+o] ----
  {
    int b = t >> 3, o0 = (t & 7) << 3;  // 8 values within one b-row
    const float* src = C + b * 68 + o0;
    unsigned int wd0 = bf16rne(src[0]) | (bf16rne(src[1]) << 16);
    unsigned int wd1 = bf16rne(src[2]) | (bf16rne(src[3]) << 16);
    unsigned int wd2 = bf16rne(src[4]) | (bf16rne(src[5]) << 16);
    unsigned int wd3 = bf16rne(src[6]) | (bf16rne(src[7]) << 16);
    unsigned short* dst = tmpb + ((size_t)hw << 12) + (t << 3);
    *(uint4*)dst = make_uint4(wd0, wd1, wd2, wd3);
  }
}

__global__ __launch_bounds__(256) void trout_k(const unsigned short* __restrict__ tmpb,
                                               const float* __restrict__ bias,
                                               float* __restrict__ out) {
  __shared__ float tile[128][65];  // [bo][hw], 33,280 B
  int bid = blockIdx.x;            // 32 bo-tiles(128) x 16 hw-tiles(64)
  int bt = bid >> 4, ht = bid & 15;
  int bo0 = bt << 7, hw0 = ht << 6;
  int lane = threadIdx.x & 63, wv = threadIdx.x >> 6;
#pragma unroll
  for (int i = 0; i < 16; ++i) {
    int r = (i << 2) + wv;  // hw row 0..63
    unsigned int u =
        *(const unsigned int*)(tmpb + (size_t)(hw0 + r) * 4096 + bo0 + 2 * lane);
    tile[2 * lane][r] = __uint_as_float(u << 16);            // bf16 lo -> f32
    tile[2 * lane + 1][r] = __uint_as_float(u & 0xFFFF0000u);  // bf16 hi -> f32
  }
  __syncthreads();
#pragma unroll
  for (int i = 0; i < 32; ++i) {
    int j = (i << 2) + wv;  // bo col 0..127
    int bo = bo0 + j;
    out[(size_t)bo * 1024 + hw0 + lane] =
        tile[j][lane] + bias[(bo & 63) * 1024 + hw0 + lane];
  }
}

extern "C" void kernel_launch(void* const* d_in, const int* in_sizes, int n_in,
                              void* d_out, int out_size, void* d_ws, size_t ws_size,
                              hipStream_t stream) {
  const float* x = (const float*)d_in[0];
  const float* wgt = (const float*)d_in[1];
  const float* bias = (const float*)d_in[2];
  float* out = (float*)d_out;
  unsigned short* xc = (unsigned short*)d_ws;                    // 8,388,608 B
  unsigned short* tmpb = (unsigned short*)((char*)d_ws + (8u << 20));  // 8,388,608 B

  const int conv_lds = 64 * PSTR * 2;  // 73,728 B dynamic LDS
  (void)hipFuncSetAttribute((const void*)conv_k,
                            hipFuncAttributeMaxDynamicSharedMemorySize, conv_lds);

  hipLaunchKernelGGL(xpose_k, dim3(512), dim3(256), 0, stream, x, xc);
  hipLaunchKernelGGL(conv_k, dim3(1024), dim3(512), conv_lds, stream, xc, wgt, tmpb);
  hipLaunchKernelGGL(trout_k, dim3(512), dim3(256), 0, stream, tmpb, bias, out);
}